// Round 1
// baseline (436.432 us; speedup 1.0000x reference)
//
#include <hip/hip_runtime.h>

// Reference: out = copy of signal (8192 x 8192 fp32). Pure D2D copy.
// 256 MiB read + 256 MiB write => roofline ~85 us at the measured ~6.4 TB/s
// achievable (harness's own fillBufferAligned hits 6.4-6.5 TB/s = 80% peak).
//
// Previous version used hipMemcpyAsync(D2D): under graph capture that becomes
// a memcpy node routed to an SDMA engine (~0.6 TB/s effective -> 425 us), NOT
// a compute blit. A plain grid-stride float4 kernel uses the full VMEM path
// (m13 ubench: 6.29 TB/s, 79% of peak for exactly this pattern).
//
// Launch config: 256 threads/block (4 waves), 2048 blocks (= 8 blocks/CU on
// 256 CUs) per Guideline 11; grid-stride covers 16M float4 (32 iters/thread).
// 16 B/lane loads => 1 KiB per wave per instruction, fully coalesced.

__global__ __launch_bounds__(256) void copy_f4_kernel(
    const float4* __restrict__ src, float4* __restrict__ dst, long n4) {
    long i = (long)blockIdx.x * blockDim.x + threadIdx.x;
    const long stride = (long)gridDim.x * blockDim.x;
    for (; i < n4; i += stride) {
        dst[i] = src[i];
    }
}

extern "C" void kernel_launch(void* const* d_in, const int* in_sizes, int n_in,
                              void* d_out, int out_size, void* d_ws, size_t ws_size,
                              hipStream_t stream) {
    const float4* src = (const float4*)d_in[0];
    float4* dst = (float4*)d_out;
    // out_size = element count (8192*8192 floats); bytes are 16-aligned.
    long n4 = (long)out_size / 4;  // 16,777,216 float4s

    const int block = 256;
    const int grid = 2048;  // 8 blocks/CU * 256 CUs; grid-stride handles rest
    hipLaunchKernelGGL(copy_f4_kernel, dim3(grid), dim3(block), 0, stream,
                       src, dst, n4);
}

// Round 3
// 412.825 us; speedup vs baseline: 1.0572x; 1.0572x over previous
//
#include <hip/hip_runtime.h>

// Reference: out = copy of signal (8192 x 8192 fp32). Pure D2D copy.
//
// Timing analysis (rounds 0-1): dur_us includes the harness's re-poison
// fills (2 x 1 GiB fillBufferAligned @ ~165 us = ~330 us, visible in
// rocprof). The copy itself is dur_us - 330:
//   round 0 hipMemcpyAsync blit : ~95 us (~5.4 TB/s)
//   round 1 grid-stride float4  : ~106 us (~4.8 TB/s)
// Floor for 512 MiB of HBM traffic at the measured 6.3-6.5 TB/s: ~82 us.
//
// One-shot kernel, no grid-stride loop. Each thread copies 4 independent
// 16 B vectors (64 B total): 4 nontemporal loads issued back-to-back (all
// in flight before the waitcnt), then 4 nontemporal stores. Accesses are
// wave-coalesced: thread t in block b touches index
//   b*1024 + k*256 + t   (k = 0..3)
// so each global_load_dwordx4 covers a contiguous, aligned 4 KiB segment
// per wave. 16384 blocks x 256 threads x 4 vec4 = 16,777,216 vec4 exactly
// (8192*8192 floats) -- no bounds checks or tail.
//
// Round-2 fix: __builtin_nontemporal_load/store requires a scalar or a
// NATIVE vector type -- HIP's float4 (HIP_vector_type struct) is rejected.
// Use clang's ext_vector_type(4) of float instead (same 16 B dwordx4).

typedef float f32x4 __attribute__((ext_vector_type(4)));

__global__ __launch_bounds__(256) void copy_f4x4_kernel(
    const f32x4* __restrict__ src, f32x4* __restrict__ dst) {
    long base = (long)blockIdx.x * 1024 + threadIdx.x;

    f32x4 a = __builtin_nontemporal_load(&src[base]);
    f32x4 b = __builtin_nontemporal_load(&src[base + 256]);
    f32x4 c = __builtin_nontemporal_load(&src[base + 512]);
    f32x4 d = __builtin_nontemporal_load(&src[base + 768]);

    __builtin_nontemporal_store(a, &dst[base]);
    __builtin_nontemporal_store(b, &dst[base + 256]);
    __builtin_nontemporal_store(c, &dst[base + 512]);
    __builtin_nontemporal_store(d, &dst[base + 768]);
}

extern "C" void kernel_launch(void* const* d_in, const int* in_sizes, int n_in,
                              void* d_out, int out_size, void* d_ws, size_t ws_size,
                              hipStream_t stream) {
    const f32x4* src = (const f32x4*)d_in[0];
    f32x4* dst = (f32x4*)d_out;
    // out_size = 8192*8192 floats = 16M vec4 = exactly 16384 blocks' worth.
    const int block = 256;
    const int grid = 16384;  // 16384 * 256 threads * 4 vec4 = out_size/4
    hipLaunchKernelGGL(copy_f4x4_kernel, dim3(grid), dim3(block), 0, stream,
                       src, dst);
}